// Round 8
// baseline (299.853 us; speedup 1.0000x reference)
//
#include <hip/hip_runtime.h>

// LiftSplatBEV: B=2, N=6, C=64, HF=112, WF=200, D=64, BEV 200x200
#define BB   2
#define NN   6
#define CCH  64
#define HFE  112
#define WFE  200
#define DDE  64
#define HWF  (HFE*WFE)      // 22400 feature pixels (= 350*64)
#define BEVH 200
#define BEVW 200
#define HWB  (BEVH*BEVW)    // 40000 BEV cells
#define ACC_ELEMS ((size_t)BB*HWB*CCH)   // channel-last [b*HWB+cell][c]

// ---------------- shared geometry (bug-faithful to reference) ----------------
struct Geo {
    int valid;
    int c00;
    float w00, w10, w01, w11;
};

__device__ __forceinline__ Geo geo_compute(int bn, int p,
    const float* __restrict__ I_inv, const float* __restrict__ E_inv,
    const float* __restrict__ Vm)
{
    Geo g; g.valid = 0; g.c00 = -1;
    g.w00 = g.w10 = g.w01 = g.w11 = 0.f;
    // bug-faithful w-outer flatten: u = p/112, v = p%112
    const float u = (float)(p / HFE);
    const float v = (float)(p % HFE);
    const float* Ii = I_inv + bn * 9;
    const float* Ei = E_inv + bn * 16;
    float cx = Ii[0]*u + Ii[1]*v + Ii[2];
    float cy = Ii[3]*u + Ii[4]*v + Ii[5];
    float cz = Ii[6]*u + Ii[7]*v + Ii[8];
    float tx = Ei[3], ty = Ei[7], tz = Ei[11];
    float dx = Ei[0]*cx + Ei[1]*cy + Ei[2] *cz + tx;   // includes translation (bug-faithful)
    float dy = Ei[4]*cx + Ei[5]*cy + Ei[6] *cz + ty;
    float dz = Ei[8]*cx + Ei[9]*cy + Ei[10]*cz + tz;
    float s  = -tz / fmaxf(dz, 1e-6f);
    float ex = tx + dx * s;
    float ey = ty + dy * s;
    float prx = Vm[0]*ex + Vm[1]*ey + Vm[2];
    float pry = Vm[3]*ex + Vm[4]*ey + Vm[5];
    float prz = Vm[6]*ex + Vm[7]*ey + Vm[8];
    float den = fmaxf(prz, 1e-7f);
    float bx = prx / den, by = pry / den;
    // bug-faithful gx->px roundtrip, same association order as reference
    float gx = bx / (float)(BEVW-1) * 2.0f - 1.0f;
    float gy = by / (float)(BEVH-1) * 2.0f - 1.0f;
    float px = (gx + 1.0f) * (float)(BEVW-1) / 2.0f;
    float py = (gy + 1.0f) * (float)(BEVH-1) / 2.0f;
    float x0f = fminf(fmaxf(floorf(px), 0.0f), (float)(BEVW-1));
    float y0f = fminf(fmaxf(floorf(py), 0.0f), (float)(BEVH-1));
    float x1f = fminf(x0f + 1.0f, (float)(BEVW-1));
    float y1f = fminf(y0f + 1.0f, (float)(BEVH-1));
    // far-edge-degenerate slots cancel exactly in the fp64 np reference: skip
    if (x0f == x1f || y0f == y1f) return g;
    float wx0 = x1f - px, wx1 = px - x0f;
    float wy0 = y1f - py, wy1 = py - y0f;
    int x0 = (int)x0f, y0 = (int)y0f;
    g.c00 = y0*BEVW + x0;
    g.w00 = wx0*wy0;  g.w10 = wx1*wy0;
    g.w01 = wx0*wy1;  g.w11 = wx1*wy1;
    // for valid pixels x1 = x0+1, y1 = y0+1 => corners = c00 + {0, 1, 200, 201}
    g.valid = 1;
    return g;
}

// ---------------- fused splat: feat-stage + depth-max + geo + run-aggregated atomics --
// Grid (350,12), block 256 (4 waves). One 64-px window per block:
//   phase 1 (parallel): feat[64ch][64px] -> LDS (coalesced over px), per-wave depth
//     partial max over 16 planes, geo for the 64 px by threads 0..63 -> LDS.
//   barrier.
//   phase 2 (per-wave serial sweep over its 16 px): bin/weights/conf broadcast from
//     LDS (wave-uniform), 4 FMA/px into run accumulators, flush 4 coalesced 256B
//     atomics on cell change. Pixel-order coherence gives the same run-aggregation
//     the sorted pipeline bought with 5 extra dispatches and 110+ MB of intermediates.
// acc (20.5 MB) is L2-resident (~2.6 MB/XCD slice) -> atomics run at L2 speed.
__global__ __launch_bounds__(256) void fused_splat_kernel(
    const float* __restrict__ feat,    // [12,64,22400]
    const float* __restrict__ depth,   // [12,64,22400]
    const float* __restrict__ I_inv, const float* __restrict__ E_inv,
    const float* __restrict__ Vm,
    float* __restrict__ acc)           // [2*HWB][64]
{
    __shared__ float fshare[64][65];   // [px][ch], stride 65
    __shared__ float cpart[4][64];     // per-wave depth partial max, [wv][px]
    __shared__ int   gbin[64];         // global bin (b*HWB + c00) or -1
    __shared__ float gwgt[64][4];      // w00,w10,w01,w11 (conf applied later)

    const int bn  = blockIdx.y;
    const int p0  = blockIdx.x * 64;           // 22400 = 350*64
    const int tid = threadIdx.x;
    const int lane = tid & 63, wv = tid >> 6;

    // ---- feat stage: each wave loads 16 channels, coalesced over px=lane
    const float* fbase = feat + (size_t)bn * CCH * HWF + p0;
#pragma unroll
    for (int c = wv; c < CCH; c += 4)
        fshare[lane][c] = fbase[(size_t)c * HWF + lane];

    // ---- depth partial max: wave wv covers planes [16wv, 16wv+16), coalesced
    const float* dbase = depth + (size_t)bn * DDE * HWF + p0;
    float m = dbase[(size_t)(wv * 16) * HWF + lane];
#pragma unroll
    for (int d = 1; d < 16; ++d)
        m = fmaxf(m, dbase[(size_t)(wv * 16 + d) * HWF + lane]);
    cpart[wv][lane] = m;

    // ---- geo: threads 0..63 compute the block's 64 pixels (once each)
    if (tid < 64) {
        Geo g = geo_compute(bn, p0 + tid, I_inv, E_inv, Vm);
        const int base = (bn / NN) * HWB;
        gbin[tid] = g.valid ? base + g.c00 : -1;
        gwgt[tid][0] = g.w00; gwgt[tid][1] = g.w10;
        gwgt[tid][2] = g.w01; gwgt[tid][3] = g.w11;
    }
    __syncthreads();

    // ---- serial sweep: wave wv handles px s in [16wv, 16wv+16)
    float a00 = 0.f, a10 = 0.f, a01 = 0.f, a11 = 0.f;
    int prev = -1;
#pragma unroll
    for (int i = 0; i < 16; ++i) {
        const int s   = wv * 16 + i;
        const int bin = gbin[s];                     // wave-uniform broadcast
        if (bin != prev) {
            if (prev >= 0) {
                float* ab = acc + (size_t)prev * CCH + lane;
                atomicAdd(ab,                     a00);
                atomicAdd(ab + (size_t)1   * CCH, a10);
                atomicAdd(ab + (size_t)200 * CCH, a01);
                atomicAdd(ab + (size_t)201 * CCH, a11);
                a00 = a10 = a01 = a11 = 0.f;
            }
            prev = bin;
        }
        if (bin >= 0) {
            const float cf = fmaxf(fmaxf(cpart[0][s], cpart[1][s]),
                                   fmaxf(cpart[2][s], cpart[3][s]));
            const float f = fshare[s][lane];
            a00 = fmaf(f, gwgt[s][0] * cf, a00);
            a10 = fmaf(f, gwgt[s][1] * cf, a10);
            a01 = fmaf(f, gwgt[s][2] * cf, a01);
            a11 = fmaf(f, gwgt[s][3] * cf, a11);
        }
    }
    if (prev >= 0) {
        float* ab = acc + (size_t)prev * CCH + lane;
        atomicAdd(ab,                     a00);
        atomicAdd(ab + (size_t)1   * CCH, a10);
        atomicAdd(ab + (size_t)200 * CCH, a01);
        atomicAdd(ab + (size_t)201 * CCH, a11);
    }
}

// G: out[b][c][cell] = acc[b*HWB+cell][c] / 6 -- float4 both sides via LDS tile
__global__ __launch_bounds__(256) void finalize_kernel(
    const float* __restrict__ acc, float* __restrict__ out)
{
    __shared__ float t[64][66];
    const int b     = blockIdx.y;
    const int cell0 = blockIdx.x * 64;
    const int cc    = threadIdx.x >> 2;   // read: cell row / write: channel
    const int q     = threadIdx.x & 3;

    const float* abase = acc + ((size_t)b * HWB + cell0) * CCH;
#pragma unroll
    for (int i = 0; i < 4; ++i) {
        const int cg = q + 4 * i;
        float4 f = *(const float4*)(abase + (size_t)cc * CCH + 4 * cg);
        t[cc][4*cg+0] = f.x; t[cc][4*cg+1] = f.y;
        t[cc][4*cg+2] = f.z; t[cc][4*cg+3] = f.w;
    }
    __syncthreads();
    float* obase = out + (size_t)b * CCH * HWB + cell0;
#pragma unroll
    for (int i = 0; i < 4; ++i) {
        const int lg = q + 4 * i;           // cell-group
        float4 o;
        o.x = t[4*lg+0][cc] * (1.0f/6.0f);
        o.y = t[4*lg+1][cc] * (1.0f/6.0f);
        o.z = t[4*lg+2][cc] * (1.0f/6.0f);
        o.w = t[4*lg+3][cc] * (1.0f/6.0f);
        *(float4*)(obase + (size_t)cc * HWB + 4 * lg) = o;
    }
}

extern "C" void kernel_launch(void* const* d_in, const int* in_sizes, int n_in,
                              void* d_out, int out_size, void* d_ws, size_t ws_size,
                              hipStream_t stream) {
    const float* feat  = (const float*)d_in[0];
    const float* depth = (const float*)d_in[1];
    const float* I_inv = (const float*)d_in[2];
    const float* E_inv = (const float*)d_in[3];
    const float* Vm    = (const float*)d_in[4];
    float* out = (float*)d_out;

    float* acc = (float*)d_ws;                     // 20.5 MB — always fits
    hipMemsetAsync(acc, 0, ACC_ELEMS * 4, stream);

    dim3 sgrid(HWF / 64, BB * NN);                 // (350,12)
    fused_splat_kernel<<<sgrid, 256, 0, stream>>>(feat, depth, I_inv, E_inv, Vm, acc);

    dim3 fgrid(HWB / 64, BB);                      // (625,2)
    finalize_kernel<<<fgrid, 256, 0, stream>>>(acc, out);
}